// Round 2
// 812.012 us; speedup vs baseline: 1.0893x; 1.0893x over previous
//
#include <hip/hip_runtime.h>
#include <math.h>

#define BATCH 32
#define SEQ   2048
#define DH    128
#define QT    64        // q rows per block (16 per wave)
#define KT    64        // k cols per iteration
#define SCALE 0.08838834764831845f   // 1/sqrt(128)

typedef _Float16 f16;
typedef _Float16 f16x4 __attribute__((ext_vector_type(4)));
typedef _Float16 f16x8 __attribute__((ext_vector_type(8)));
typedef float    f32x4 __attribute__((ext_vector_type(4)));

// async global->LDS, 16B per lane; dest = wave-uniform base + lane*16.
// Direct generic->AS(3) cast (addrspacecast) — no integer truncation games.
__device__ __forceinline__ void gld16(const void* g, void* l) {
    __builtin_amdgcn_global_load_lds(
        (const __attribute__((address_space(1))) unsigned int*)g,
        (__attribute__((address_space(3))) unsigned int*)l,
        16, 0, 0);
}

// ---------------- pre-pass 1: K fp32 -> fp16 (same layout) ----------------
__global__ __launch_bounds__(256)
void cvt_k_kernel(const float* __restrict__ src, f16* __restrict__ dst) {
    size_t i = ((size_t)blockIdx.x * 256 + threadIdx.x) * 8;
    f32x4 a = *(const f32x4*)&src[i];
    f32x4 c = *(const f32x4*)&src[i + 4];
    f16x8 h = { (f16)a.x,(f16)a.y,(f16)a.z,(f16)a.w,(f16)c.x,(f16)c.y,(f16)c.z,(f16)c.w };
    *(f16x8*)&dst[i] = h;
}

// ---------------- pre-pass 2: V fp32 [B][S][D] -> fp16 [B][D][S] ----------
__global__ __launch_bounds__(256)
void tr_v_kernel(const float* __restrict__ v, f16* __restrict__ vt) {
    __shared__ f16 t[128 * 80];          // [d][s-tile], stride 80 halves
    const int tid  = threadIdx.x;
    const int srow = tid >> 5, scol = tid & 31;
    const int b  = blockIdx.x >> 5;
    const int s0 = (blockIdx.x & 31) * 64;
    const size_t base = (size_t)b * SEQ * DH;
    #pragma unroll
    for (int p = 0; p < 8; ++p) {
        int j = p * 8 + srow;
        const float* vr = &v[base + (size_t)(s0 + j) * DH];
        #pragma unroll
        for (int i = 0; i < 4; ++i)
            t[(scol + 32 * i) * 80 + j] = (f16)vr[scol + 32 * i];
    }
    __syncthreads();
    #pragma unroll
    for (int p = 0; p < 4; ++p) {
        int c = p * 256 + tid;
        int d = c >> 3, col = (c & 7) * 8;
        f16x8 h = *(const f16x8*)&t[d * 80 + col];
        *(f16x8*)&vt[(size_t)b * DH * SEQ + (size_t)d * SEQ + s0 + col] = h;
    }
}

// ---------------- main kernel: S^T layout, gload_lds staging, swizzled LDS -
// LDS: ks 64x128h (16KB) + vs 128x64h (16KB) + ps 4x16x64h (8KB) = 40960 B
//      -> 4 blocks/CU (16 waves). All tiles XOR-swizzled: byte ^= (row&7)<<4.
__global__ __launch_bounds__(256, 4)
void ScaledDotProductAttention_46720654246409_kernel(
    const float* __restrict__ q, const f16* __restrict__ k16,
    const f16* __restrict__ vt16, const float* __restrict__ mask,
    float* __restrict__ out)
{
    __shared__ f16 ks[64 * 128];
    __shared__ f16 vs[128 * 64];
    __shared__ f16 ps[4 * 16 * 64];

    const int tid  = threadIdx.x;
    const int wv   = tid >> 6;
    const int lane = tid & 63;
    const int quad = lane >> 4;
    const int l16  = lane & 15;
    const int m3   = l16 & 7;            // read-side swizzle key
    const int srow = tid >> 5;
    const int scol = tid & 31;

    const int bidx = blockIdx.x;
    const int b    = bidx >> 5;
    const int q0   = (bidx & 31) * QT;

    const size_t qkvBase = (size_t)b * SEQ * DH;
    const size_t mBase   = (size_t)b * SEQ * SEQ;

    char* ksb = (char*)ks;
    char* vsb = (char*)vs;
    char* psb = (char*)ps + wv * 2048;

    // ---- stage Q (fp32->fp16) through ks (swizzled), pull A/B-frags ----
    #pragma unroll
    for (int p = 0; p < 8; ++p) {
        int r = p * 8 + srow;
        f32x4 x = *(const f32x4*)&q[qkvBase + (size_t)(q0 + r) * DH + scol * 4];
        f16x4 h = { (f16)x.x, (f16)x.y, (f16)x.z, (f16)x.w };
        *(f16x4*)(ksb + r * 256 + ((scol * 8) ^ ((r & 7) << 4))) = h;
    }
    __syncthreads();

    f16x8 aq[4];   // Q frag: lane holds q-row (wv*16+l16), d = dc*32 + quad*8 + j
    #pragma unroll
    for (int dc = 0; dc < 4; ++dc)
        aq[dc] = *(const f16x8*)(ksb + (wv * 16 + l16) * 256 + ((dc * 64 + quad * 16) ^ (m3 << 4)));
    __syncthreads();

    float m_run = -INFINITY, l_run = 0.f;
    f32x4 o[8];
    #pragma unroll
    for (int f = 0; f < 8; ++f) o[f] = (f32x4){0.f, 0.f, 0.f, 0.f};

    const f16* kbase = k16  + qkvBase;
    const f16* vbase = vt16 + (size_t)b * DH * SEQ;

    #pragma unroll 1
    for (int kt = 0; kt < SEQ / KT; ++kt) {
        const int k0 = kt * KT;

        // ---- async stage K tile: 16 chunks x 1024B, wave wv -> chunks wv*4..+3
        // linear LDS dest; source pre-swizzled so read-side XOR recovers data
        #pragma unroll
        for (int i = 0; i < 4; ++i) {
            int c   = wv * 4 + i;
            int row = c * 4 + (lane >> 4);          // k-row 0..63
            gld16(kbase + (size_t)(k0 + row) * DH + 8 * ((lane & 15) ^ (row & 7)),
                  ksb + c * 1024);
        }
        // ---- async stage Vt tile (rows = d 0..127, 64 halves of s each)
        #pragma unroll
        for (int i = 0; i < 4; ++i) {
            int c   = wv * 4 + i;
            int row = c * 8 + (lane >> 3);          // d-row 0..127
            gld16(vbase + (size_t)row * SEQ + k0 + 8 * ((lane & 7) ^ (row & 7)),
                  vsb + c * 1024);
        }

        // ---- mask: lane owns q-row l16 -> 4x float4 contiguous in k ----
        f32x4 mk[4];
        const float* mrow = &mask[mBase + (size_t)(q0 + wv * 16 + l16) * SEQ + k0 + quad * 4];
        #pragma unroll
        for (int f = 0; f < 4; ++f)
            mk[f] = __builtin_nontemporal_load((const f32x4*)(mrow + f * 16));

        __syncthreads();   // drains gload_lds (vmcnt) + mask loads

        // ---- S^T = K Q^T : C col = q (l16), C row = k (quad*4+r, f*16 tiles)
        f32x4 sc[4];
        #pragma unroll
        for (int f = 0; f < 4; ++f) {
            sc[f] = (f32x4){0.f, 0.f, 0.f, 0.f};
            #pragma unroll
            for (int dc = 0; dc < 4; ++dc) {
                f16x8 kf = *(const f16x8*)(ksb + (f * 16 + l16) * 256 +
                                           ((dc * 64 + quad * 16) ^ (m3 << 4)));
                sc[f] = __builtin_amdgcn_mfma_f32_16x16x32_f16(kf, aq[dc], sc[f], 0, 0, 0);
            }
        }

        // ---- online softmax: lane owns q-row l16; reduce across quads ----
        float sf[4][4];
        float mx = -INFINITY;
        #pragma unroll
        for (int f = 0; f < 4; ++f)
            #pragma unroll
            for (int r = 0; r < 4; ++r) {
                sf[f][r] = sc[f][r] * SCALE * mk[f][r];
                mx = fmaxf(mx, sf[f][r]);
            }
        mx = fmaxf(mx, __shfl_xor(mx, 16));
        mx = fmaxf(mx, __shfl_xor(mx, 32));
        float mn = fmaxf(m_run, mx);
        float al = __expf(m_run - mn);           // first iter: exp(-inf) = 0
        float sum = 0.f;
        float pv[4][4];
        #pragma unroll
        for (int f = 0; f < 4; ++f)
            #pragma unroll
            for (int r = 0; r < 4; ++r) { pv[f][r] = __expf(sf[f][r] - mn); sum += pv[f][r]; }
        sum += __shfl_xor(sum, 16);
        sum += __shfl_xor(sum, 32);
        m_run = mn;
        l_run = l_run * al + sum;
        // redistribute alpha to O-layout rows (O row q=quad*4+r lives in lane l16=q)
        float alpha[4];
        #pragma unroll
        for (int r = 0; r < 4; ++r) alpha[r] = __shfl(al, quad * 4 + r, 16);

        // ---- P -> ps [q=l16 row][k halves] (swizzled), then A-frags ----
        #pragma unroll
        for (int f = 0; f < 4; ++f) {
            f16x4 pk = { (f16)pv[f][0], (f16)pv[f][1], (f16)pv[f][2], (f16)pv[f][3] };
            *(f16x4*)(psb + l16 * 128 + ((f * 32 + quad * 8) ^ (m3 << 4))) = pk;
        }
        asm volatile("s_waitcnt lgkmcnt(0)" ::: "memory");

        f16x8 ap0 = *(const f16x8*)(psb + l16 * 128 + ((quad * 16) ^ (m3 << 4)));
        f16x8 ap1 = *(const f16x8*)(psb + l16 * 128 + ((64 + quad * 16) ^ (m3 << 4)));

        // ---- O = O*alpha + P V ----
        #pragma unroll
        for (int f = 0; f < 8; ++f) {
            #pragma unroll
            for (int r = 0; r < 4; ++r) o[f][r] *= alpha[r];
            const char* vrow = vsb + (f * 16 + l16) * 128;
            f16x8 bv0 = *(const f16x8*)(vrow + ((quad * 16) ^ (m3 << 4)));
            f16x8 bv1 = *(const f16x8*)(vrow + ((64 + quad * 16) ^ (m3 << 4)));
            o[f] = __builtin_amdgcn_mfma_f32_16x16x32_f16(ap0, bv0, o[f], 0, 0, 0);
            o[f] = __builtin_amdgcn_mfma_f32_16x16x32_f16(ap1, bv1, o[f], 0, 0, 0);
        }
        __syncthreads();
    }

    // ---- epilogue ----
    float linv[4];
    #pragma unroll
    for (int r = 0; r < 4; ++r) linv[r] = 1.0f / __shfl(l_run, quad * 4 + r, 16);
    #pragma unroll
    for (int r = 0; r < 4; ++r)
        #pragma unroll
        for (int f = 0; f < 8; ++f)
            __builtin_nontemporal_store(o[f][r] * linv[r],
                &out[qkvBase + (size_t)(q0 + wv * 16 + quad * 4 + r) * DH + f * 16 + l16]);
}

// ---------------- fallback (round-0 verified kernel) if ws too small ------
__global__ __launch_bounds__(256, 3)
void attn_fallback_kernel(
    const float* __restrict__ q, const float* __restrict__ k,
    const float* __restrict__ v, const float* __restrict__ mask,
    float* __restrict__ out)
{
    __shared__ f16 ks[KT * 136];
    __shared__ f16 vs[DH * 72];
    __shared__ f16 ps[4 * 16 * 72];

    const int tid  = threadIdx.x;
    const int wv   = tid >> 6;
    const int lane = tid & 63;
    const int quad = lane >> 4;
    const int l16  = lane & 15;
    const int srow = tid >> 5;
    const int scol = tid & 31;

    const int bidx = blockIdx.x;
    const int b    = bidx >> 5;
    const int q0   = (bidx & 31) * QT;

    const size_t qkvBase = (size_t)b * SEQ * DH;
    const size_t mBase   = (size_t)b * SEQ * SEQ;

    #pragma unroll
    for (int p = 0; p < 8; ++p) {
        int r = p * 8 + srow;
        f32x4 x = *(const f32x4*)&q[qkvBase + (size_t)(q0 + r) * DH + scol * 4];
        f16x4 h = { (f16)x.x, (f16)x.y, (f16)x.z, (f16)x.w };
        *(f16x4*)&ks[r * 136 + scol * 4] = h;
    }
    __syncthreads();

    f16x8 aq[4];
    #pragma unroll
    for (int dc = 0; dc < 4; ++dc)
        aq[dc] = *(const f16x8*)&ks[(wv * 16 + l16) * 136 + dc * 32 + quad * 8];
    __syncthreads();

    float m_run[4] = { -INFINITY, -INFINITY, -INFINITY, -INFINITY };
    float l_run[4] = { 0.f, 0.f, 0.f, 0.f };
    f32x4 o[8];
    #pragma unroll
    for (int f = 0; f < 8; ++f) o[f] = (f32x4){0.f, 0.f, 0.f, 0.f};

    for (int kt = 0; kt < SEQ / KT; ++kt) {
        const int k0 = kt * KT;

        float mk[4][4];
        #pragma unroll
        for (int f = 0; f < 4; ++f)
            #pragma unroll
            for (int r = 0; r < 4; ++r)
                mk[f][r] = mask[mBase + (size_t)(q0 + wv*16 + quad*4 + r) * SEQ
                                + k0 + f*16 + l16];

        #pragma unroll
        for (int p = 0; p < 8; ++p) {
            int r = p * 8 + srow;
            f32x4 x = *(const f32x4*)&k[qkvBase + (size_t)(k0 + r) * DH + scol * 4];
            f16x4 h = { (f16)x.x, (f16)x.y, (f16)x.z, (f16)x.w };
            *(f16x4*)&ks[r * 136 + scol * 4] = h;
        }
        #pragma unroll
        for (int p = 0; p < 8; ++p) {
            int j = p * 8 + srow;
            const float* vr = &v[qkvBase + (size_t)(k0 + j) * DH];
            #pragma unroll
            for (int i = 0; i < 4; ++i)
                vs[(scol + 32*i) * 72 + j] = (f16)vr[scol + 32*i];
        }
        __syncthreads();

        f32x4 sc[4];
        #pragma unroll
        for (int f = 0; f < 4; ++f) {
            sc[f] = (f32x4){0.f, 0.f, 0.f, 0.f};
            #pragma unroll
            for (int dc = 0; dc < 4; ++dc) {
                f16x8 bk = *(const f16x8*)&ks[(f*16 + l16) * 136 + dc*32 + quad*8];
                sc[f] = __builtin_amdgcn_mfma_f32_16x16x32_f16(aq[dc], bk, sc[f], 0, 0, 0);
            }
        }

        float pj[4][4];
        float alpha[4];
        #pragma unroll
        for (int r = 0; r < 4; ++r) {
            float sf[4];
            #pragma unroll
            for (int f = 0; f < 4; ++f) sf[f] = sc[f][r] * SCALE * mk[f][r];
            float mx = fmaxf(fmaxf(sf[0], sf[1]), fmaxf(sf[2], sf[3]));
            #pragma unroll
            for (int off = 1; off < 16; off <<= 1)
                mx = fmaxf(mx, __shfl_xor(mx, off, 16));
            float mn = fmaxf(m_run[r], mx);
            float al = __expf(m_run[r] - mn);
            float sum = 0.f;
            #pragma unroll
            for (int f = 0; f < 4; ++f) { pj[f][r] = __expf(sf[f] - mn); sum += pj[f][r]; }
            #pragma unroll
            for (int off = 1; off < 16; off <<= 1)
                sum += __shfl_xor(sum, off, 16);
            m_run[r] = mn;
            l_run[r] = l_run[r] * al + sum;
            alpha[r] = al;
        }

        #pragma unroll
        for (int f = 0; f < 4; ++f)
            #pragma unroll
            for (int r = 0; r < 4; ++r)
                ps[(wv*16 + quad*4 + r) * 72 + f*16 + l16] = (f16)pj[f][r];
        asm volatile("s_waitcnt lgkmcnt(0)" ::: "memory");

        f16x8 ap0 = *(const f16x8*)&ps[(wv*16 + l16) * 72 + quad*8];
        f16x8 ap1 = *(const f16x8*)&ps[(wv*16 + l16) * 72 + 32 + quad*8];

        #pragma unroll
        for (int f = 0; f < 8; ++f) {
            #pragma unroll
            for (int r = 0; r < 4; ++r) o[f][r] *= alpha[r];
            f16x8 bv0 = *(const f16x8*)&vs[(f*16 + l16) * 72 + quad*8];
            f16x8 bv1 = *(const f16x8*)&vs[(f*16 + l16) * 72 + 32 + quad*8];
            o[f] = __builtin_amdgcn_mfma_f32_16x16x32_f16(ap0, bv0, o[f], 0, 0, 0);
            o[f] = __builtin_amdgcn_mfma_f32_16x16x32_f16(ap1, bv1, o[f], 0, 0, 0);
        }
        __syncthreads();
    }

    #pragma unroll
    for (int r = 0; r < 4; ++r) {
        float inv = 1.0f / l_run[r];
        #pragma unroll
        for (int f = 0; f < 8; ++f)
            out[qkvBase + (size_t)(q0 + wv*16 + quad*4 + r) * DH + f*16 + l16]
                = o[f][r] * inv;
    }
}

extern "C" void kernel_launch(void* const* d_in, const int* in_sizes, int n_in,
                              void* d_out, int out_size, void* d_ws, size_t ws_size,
                              hipStream_t stream) {
    const float* q    = (const float*)d_in[0];
    const float* k    = (const float*)d_in[1];
    const float* v    = (const float*)d_in[2];
    const float* mask = (const float*)d_in[3];
    float* out = (float*)d_out;

    const size_t elems = (size_t)BATCH * SEQ * DH;    // 8,388,608
    if (d_ws && ws_size >= 2 * elems * sizeof(f16)) { // 33.5 MB needed
        f16* k16  = (f16*)d_ws;
        f16* vt16 = k16 + elems;
        hipLaunchKernelGGL(cvt_k_kernel, dim3((unsigned)(elems / 2048)), dim3(256), 0, stream,
                           k, k16);
        hipLaunchKernelGGL(tr_v_kernel, dim3(BATCH * (SEQ / 64)), dim3(256), 0, stream,
                           v, vt16);
        hipLaunchKernelGGL(ScaledDotProductAttention_46720654246409_kernel,
                           dim3(BATCH * (SEQ / QT)), dim3(256), 0, stream,
                           q, k16, vt16, mask, out);
    } else {
        hipLaunchKernelGGL(attn_fallback_kernel,
                           dim3(BATCH * (SEQ / QT)), dim3(256), 0, stream,
                           q, k, v, mask, out);
    }
}